// Round 5
// baseline (297.954 us; speedup 1.0000x reference)
//
#include <hip/hip_runtime.h>
#include <hip/hip_bf16.h>
#include <math.h>

typedef unsigned short u16;
typedef short short8 __attribute__((ext_vector_type(8)));
typedef float floatx4 __attribute__((ext_vector_type(4)));

#define B_   2
#define S_   2048
#define DM_  2048
#define H_   16
#define KVH_ 4
#define HD_  128

__device__ __forceinline__ float bf2f(u16 v) {
  union { unsigned int u; float f; } x; x.u = ((unsigned int)v) << 16; return x.f;
}
__device__ __forceinline__ u16 f2bf(float f) {
  union { float f; unsigned int u; } x; x.f = f;
  unsigned int u = x.u;
  u += 0x7FFFu + ((u >> 16) & 1u);   // RNE; inputs finite
  return (u16)(u >> 16);
}

// async 16B global->LDS (lds dest = wave-uniform base + lane*16)
#define GLDS16(gp, lp) __builtin_amdgcn_global_load_lds( \
    (const __attribute__((address_space(1))) unsigned int*)(const void*)(gp), \
    (__attribute__((address_space(3))) unsigned int*)(void*)(lp), 16, 0, 0)

// ---------------------------------------------------------------------------
// k_prep: pack_x (blocks 0..8191) + 4 weight transposes (8192..18431) +
// RoPE sincos table (18432..18943): tab[pos][fi] = (cos, sin), 1 MB.
// ---------------------------------------------------------------------------
__global__ __launch_bounds__(256) void k_prep(
    const float* __restrict__ x, const float* __restrict__ wq,
    const float* __restrict__ wk, const float* __restrict__ wv,
    const float* __restrict__ wo,
    u16* __restrict__ x_bf, u16* __restrict__ wqkv_t, u16* __restrict__ wo_t,
    float2* __restrict__ rope_tab)
{
  int bx = blockIdx.x;
  if (bx >= 18432) {                     // RoPE table: 2048 pos x 64 freq
    int idx = (bx - 18432) * 256 + threadIdx.x;
    int pos = idx >> 6;
    float fi = (float)(idx & 63);
    float ts = powf(10000.0f, fi * (1.0f / 64.0f));
    float ang = (float)pos / ts;
    rope_tab[idx] = make_float2(cosf(ang), sinf(ang));
    return;
  }
  if (bx < 8192) {                       // x -> bf16, 4 elems/thread
    int i = bx * 256 + threadIdx.x;
    const float4 v = ((const float4*)x)[i];
    u16 o[4] = { f2bf(v.x), f2bf(v.y), f2bf(v.z), f2bf(v.w) };
    *(unsigned long long*)(x_bf + (size_t)i * 4) = *(unsigned long long*)o;
    return;
  }
  bx -= 8192;
  const float* src; u16* dst; int C, cb;
  if (bx < 4096)      { src = wq; dst = wqkv_t; C = 2048; cb = 64; }
  else if (bx < 5120) { bx -= 4096; src = wk; dst = wqkv_t + (size_t)2048 * 2048; C = 512; cb = 16; }
  else if (bx < 6144) { bx -= 5120; src = wv; dst = wqkv_t + (size_t)2560 * 2048; C = 512; cb = 16; }
  else                { bx -= 6144; src = wo; dst = wo_t; C = 2048; cb = 64; }
  const int R = 2048;
  int c0 = (bx % cb) * 32, r0 = (bx / cb) * 32;
  __shared__ float tile[32][33];
  int tx = threadIdx.x & 31, ty = threadIdx.x >> 5;
#pragma unroll
  for (int j = 0; j < 4; j++)
    tile[ty * 4 + j][tx] = src[(size_t)(r0 + ty * 4 + j) * C + c0 + tx];
  __syncthreads();
#pragma unroll
  for (int j = 0; j < 4; j++)
    dst[(size_t)(c0 + ty * 4 + j) * R + r0 + tx] = f2bf(tile[tx][ty * 4 + j]);
}

// ---------------------------------------------------------------------------
// GEMM (generic, used for att@wo): C[M][N] = A[M][K]*Bt[N][K]^T, f32/bf16 out
// 128x128 tile, BK=64, GLDS staging, chunk^(row&7) swizzle.
// ---------------------------------------------------------------------------
__global__ __launch_bounds__(256, 3) void k_gemm_bt(
    const u16* __restrict__ A, const u16* __restrict__ Bt,
    void* __restrict__ Cout, int M, int N, int K, int c_bf16)
{
  __shared__ u16 As[128 * 64];
  __shared__ u16 Bs[128 * 64];
  int tid = threadIdx.x;
  int lane = tid & 63;
  int quad = lane >> 4, l16 = lane & 15;
  int wid = tid >> 6;
  int m0 = blockIdx.y * 128, n0 = blockIdx.x * 128;
  int wm = (wid >> 1) * 64, wn = (wid & 1) * 64;

  floatx4 acc[4][4] = {};

  int srow = tid >> 3;
  int gjc0 = (tid & 7) ^ (srow & 7);
  const u16* Ap = A + (size_t)(m0 + srow) * K + gjc0 * 8;
  const u16* Bp = Bt + (size_t)(n0 + srow) * K + gjc0 * 8;
  u16* AsW = As + tid * 8;
  u16* BsW = Bs + tid * 8;

  for (int kt = 0; kt < K; kt += 64) {
    __syncthreads();
#pragma unroll
    for (int j = 0; j < 4; j++) {
      GLDS16(Ap + (size_t)(j * 32) * K, AsW + j * 2048);
      GLDS16(Bp + (size_t)(j * 32) * K, BsW + j * 2048);
    }
    Ap += 64; Bp += 64;
    __syncthreads();

#pragma unroll
    for (int ks = 0; ks < 2; ks++) {
      short8 af[4], bfv[4];
#pragma unroll
      for (int mi = 0; mi < 4; mi++) {
        int row = wm + mi * 16 + l16;
        af[mi] = *(const short8*)&As[row * 64 + (((ks * 4 + quad) ^ (row & 7)) * 8)];
      }
#pragma unroll
      for (int ni = 0; ni < 4; ni++) {
        int row = wn + ni * 16 + l16;
        bfv[ni] = *(const short8*)&Bs[row * 64 + (((ks * 4 + quad) ^ (row & 7)) * 8)];
      }
#pragma unroll
      for (int mi = 0; mi < 4; mi++)
#pragma unroll
        for (int ni = 0; ni < 4; ni++)
          acc[mi][ni] = __builtin_amdgcn_mfma_f32_16x16x32_bf16(
              af[mi], bfv[ni], acc[mi][ni], 0, 0, 0);
    }
  }

#pragma unroll
  for (int mi = 0; mi < 4; mi++)
#pragma unroll
    for (int ni = 0; ni < 4; ni++)
#pragma unroll
      for (int r = 0; r < 4; r++) {
        int row = m0 + wm + mi * 16 + quad * 4 + r;
        int col = n0 + wn + ni * 16 + l16;
        float v = acc[mi][ni][r];
        if (c_bf16) ((u16*)Cout)[(size_t)row * N + col] = f2bf(v);
        else        ((float*)Cout)[(size_t)row * N + col] = v;
      }
}

// ---------------------------------------------------------------------------
// k_gemm_qkv: x_bf @ [wq|wk|wv]^T with FUSED RMSNorm+RoPE epilogue.
// N-tile (128 cols) == exactly one head. RoPE pair (d, d+64) sits in the
// SAME lane / SAME acc slot of the wave pair (wid, wid^1) -> exchange via
// 16 KB LDS overlay (lane-contiguous f32 [16][256], conflict-free), one
// mi-slice at a time (keeps +16 VGPR only). sincos from precomputed table.
// f32 accumulators feed the norm directly (more accurate than bf16 C1 trip).
// v-tiles (nt 20..23) keep the old C1 bf16 store for pack_vt.
// ---------------------------------------------------------------------------
__global__ __launch_bounds__(256, 3) void k_gemm_qkv(
    const u16* __restrict__ A, const u16* __restrict__ Bt,
    const float* __restrict__ qs, const float* __restrict__ ks,
    const float2* __restrict__ tab,
    u16* __restrict__ C1, u16* __restrict__ qr, u16* __restrict__ kr)
{
  const int K = 2048, N = 3072;
  __shared__ u16 smem[16384] __attribute__((aligned(16)));   // As@0, Bs@8192
  u16* As = smem;
  u16* Bs = smem + 8192;
  float* exch = (float*)smem;        // epilogue overlay: [16][256] f32, 16 KB

  int tid = threadIdx.x;
  int lane = tid & 63;
  int quad = lane >> 4, l16 = lane & 15;
  int wid = tid >> 6;
  int m0 = blockIdx.y * 128, n0 = blockIdx.x * 128;
  int wm = (wid >> 1) * 64, wn = (wid & 1) * 64;

  floatx4 acc[4][4] = {};

  int srow = tid >> 3;
  int gjc0 = (tid & 7) ^ (srow & 7);
  const u16* Ap = A + (size_t)(m0 + srow) * K + gjc0 * 8;
  const u16* Bp = Bt + (size_t)(n0 + srow) * K + gjc0 * 8;
  u16* AsW = As + tid * 8;
  u16* BsW = Bs + tid * 8;

  for (int kt = 0; kt < K; kt += 64) {
    __syncthreads();
#pragma unroll
    for (int j = 0; j < 4; j++) {
      GLDS16(Ap + (size_t)(j * 32) * K, AsW + j * 2048);
      GLDS16(Bp + (size_t)(j * 32) * K, BsW + j * 2048);
    }
    Ap += 64; Bp += 64;
    __syncthreads();

#pragma unroll
    for (int ks = 0; ks < 2; ks++) {
      short8 af[4], bfv[4];
#pragma unroll
      for (int mi = 0; mi < 4; mi++) {
        int row = wm + mi * 16 + l16;
        af[mi] = *(const short8*)&As[row * 64 + (((ks * 4 + quad) ^ (row & 7)) * 8)];
      }
#pragma unroll
      for (int ni = 0; ni < 4; ni++) {
        int row = wn + ni * 16 + l16;
        bfv[ni] = *(const short8*)&Bs[row * 64 + (((ks * 4 + quad) ^ (row & 7)) * 8)];
      }
#pragma unroll
      for (int mi = 0; mi < 4; mi++)
#pragma unroll
        for (int ni = 0; ni < 4; ni++)
          acc[mi][ni] = __builtin_amdgcn_mfma_f32_16x16x32_bf16(
              af[mi], bfv[ni], acc[mi][ni], 0, 0, 0);
    }
  }

  int nt = blockIdx.x;               // head index (q: 0..15, k: 16..19, v: 20..23)
  if (nt >= 20) {                    // v-tiles: plain bf16 store to C1
#pragma unroll
    for (int mi = 0; mi < 4; mi++)
#pragma unroll
      for (int ni = 0; ni < 4; ni++)
#pragma unroll
        for (int r = 0; r < 4; r++) {
          int row = m0 + wm + mi * 16 + quad * 4 + r;
          int col = n0 + wn + ni * 16 + l16;
          C1[(size_t)row * N + col] = f2bf(acc[mi][ni][r]);
        }
    return;
  }

  // fused RMSNorm + RoPE epilogue (q/k heads)
  bool isq = nt < 16;
  const float* scp = isq ? qs : ks;
  float sc_own[4], sc_par[4];
#pragma unroll
  for (int ni = 0; ni < 4; ni++) {
    sc_own[ni] = scp[wn + ni * 16 + l16];
    sc_par[ni] = scp[(wn ^ 64) + ni * 16 + l16];
  }
  float ssign = (wn == 0) ? -1.0f : 1.0f;   // d<64: y*c - p*s ; d>=64: y*c + p*s

#pragma unroll
  for (int mi = 0; mi < 4; mi++) {
    __syncthreads();                 // prior round's reads (or K-loop) done
#pragma unroll
    for (int ni = 0; ni < 4; ni++)
#pragma unroll
      for (int r = 0; r < 4; r++)
        exch[(ni * 4 + r) * 256 + wid * 64 + lane] = acc[mi][ni][r];
    __syncthreads();
    float part[4][4];
#pragma unroll
    for (int ni = 0; ni < 4; ni++)
#pragma unroll
      for (int r = 0; r < 4; r++)
        part[ni][r] = exch[(ni * 4 + r) * 256 + (wid ^ 1) * 64 + lane];

#pragma unroll
    for (int r = 0; r < 4; r++) {
      float ss = 0.f;
#pragma unroll
      for (int ni = 0; ni < 4; ni++)
        ss += acc[mi][ni][r] * acc[mi][ni][r] + part[ni][r] * part[ni][r];
#pragma unroll
      for (int d = 1; d < 16; d <<= 1) ss += __shfl_xor(ss, d);
      float rs = rsqrtf(ss * (1.0f / 128.0f) + 1e-6f);
      int row = m0 + wm + mi * 16 + quad * 4 + r;
      int pos = row & (S_ - 1);
#pragma unroll
      for (int ni = 0; ni < 4; ni++) {
        float2 cs = tab[pos * 64 + ni * 16 + l16];
        float yo = acc[mi][ni][r] * rs * sc_own[ni];
        float yp = part[ni][r] * rs * sc_par[ni];
        float o = fmaf(ssign * yp, cs.y, yo * cs.x);
        if (isq) o *= 0.088388347648318447f;
        int d = wn + ni * 16 + l16;
        if (isq) qr[((size_t)row * H_ + nt) * HD_ + d] = f2bf(o);
        else     kr[((size_t)row * KVH_ + (nt - 16)) * HD_ + d] = f2bf(o);
      }
    }
  }
}

// ---------------------------------------------------------------------------
// k_vt: pack_vt only (RMSNorm+RoPE moved into k_gemm_qkv epilogue).
// ---------------------------------------------------------------------------
__global__ __launch_bounds__(256) void k_vt(
    const u16* __restrict__ C1, u16* __restrict__ vt)
{
  int bx = blockIdx.x;                   // [0, 2048)
  int sx = bx & 63, rest = bx >> 6;
  int hy = rest & 3, bk = rest >> 2;
  int s0 = sx * 32, h0 = hy * 32;
  int b = bk >> 2, kv = bk & 3;
  __shared__ u16 tile[32][33];
  int tx = threadIdx.x & 31, ty = threadIdx.x >> 5;
#pragma unroll
  for (int j = 0; j < 4; j++)
    tile[ty * 4 + j][tx] =
        C1[(size_t)(b * S_ + s0 + ty * 4 + j) * 3072 + 2560 + kv * HD_ + h0 + tx];
  __syncthreads();
#pragma unroll
  for (int j = 0; j < 4; j++)
    vt[((size_t)bk * HD_ + h0 + ty * 4 + j) * S_ + s0 + tx] = tile[tx][ty * 4 + j];
}

// ---------------------------------------------------------------------------
// Flash attention v5 (unchanged from round 4: zero bank conflicts):
// 1024 blocks x 4 waves, 64 q-rows/block, waves split (row-half, s-half),
// GLDS double-buffered K/V, Ps [32][64] chunk^(prow&7), rotated epilogue
// exchange.  FIXED-MAX softmax (|score| <= 11.32 post-RMSNorm).
// ---------------------------------------------------------------------------
__global__ __launch_bounds__(256, 2) void k_flash(
    const u16* __restrict__ qr, const u16* __restrict__ kr,
    const u16* __restrict__ vt, u16* __restrict__ att)
{
  __shared__ u16 smem[40960] __attribute__((aligned(16)));
  u16* Ps = smem + 32768;
  float* lpbuf = (float*)(smem + 32768);   // overlays Ps (dead in epilogue)

  int tid = threadIdx.x, lane = tid & 63, wid = tid >> 6;
  int quad = lane >> 4, l16 = lane & 15;
  int rhalf = wid & 1;
  int shalf = wid >> 1;
  int bx = blockIdx.x;
  int it = 31 - (bx >> 5);
  int hb = bx & 31;
  int h = hb & 15, b = hb >> 4;
  int kvh = h >> 2;
  int q0 = it * 64;
  int NT = it + 1;

  short8 qf[2][4];
#pragma unroll
  for (int m = 0; m < 2; m++) {
    const u16* qb = qr + ((size_t)(b * S_ + q0 + rhalf * 32 + m * 16 + l16) * H_ + h) * HD_;
#pragma unroll
    for (int kk = 0; kk < 4; kk++)
      qf[m][kk] = *(const short8*)(qb + kk * 32 + quad * 8);
  }

  int gjk = (tid & 15) ^ ((tid >> 4) & 15);
  int gjv = (tid & 7) ^ ((tid >> 3) & 7);
  const u16* kp = kr + ((size_t)(b * S_ + (tid >> 4)) * KVH_ + kvh) * HD_ + gjk * 8;
  const u16* vp = vt + ((size_t)(b * KVH_ + kvh) * HD_ + (tid >> 3)) * S_ + gjv * 8;

#pragma unroll
  for (int j = 0; j < 4; j++) {
    GLDS16(kp + (size_t)(j * 16) * KVH_ * HD_, smem + (size_t)(j * 256 + tid) * 8);
    GLDS16(vp + (size_t)(j * 32) * S_,         smem + 16384 + (size_t)(j * 256 + tid) * 8);
  }
  kp += (size_t)64 * KVH_ * HD_;
  vp += 64;
  __syncthreads();

  floatx4 accO[2][8] = {};
  float lp[2][4] = {};
  u16* PsW = Ps + wid * 2048;

  const float LOG2E = 1.4426950408889634f;
  const float MBIAS = -12.5f * 1.4426950408889634f;
  int qmax = q0 + rhalf * 32 + 31;

  for (int kt = 0; kt < NT; kt++) {
    if (kt + 1 < NT) {
      u16* KD = smem + (size_t)((kt + 1) & 1) * 8192;
      u16* VD = smem + 16384 + (size_t)((kt + 1) & 1) * 8192;
#pragma unroll
      for (int j = 0; j < 4; j++) {
        GLDS16(kp + (size_t)(j * 16) * KVH_ * HD_, KD + (size_t)(j * 256 + tid) * 8);
        GLDS16(vp + (size_t)(j * 32) * S_,         VD + (size_t)(j * 256 + tid) * 8);
      }
      kp += (size_t)64 * KVH_ * HD_;
      vp += 64;
    }

    int k0 = kt * 64;
    int s0w = k0 + shalf * 32;
    if (s0w <= qmax) {
      const u16* KsC = smem + (size_t)(kt & 1) * 8192;
      const u16* VtC = smem + 16384 + (size_t)(kt & 1) * 8192;

      floatx4 sacc[2][2] = {};
      __builtin_amdgcn_s_setprio(1);
#pragma unroll
      for (int kk = 0; kk < 4; kk++) {
        short8 kf[2];
#pragma unroll
        for (int nt = 0; nt < 2; nt++) {
          int row = shalf * 32 + nt * 16 + l16;
          kf[nt] = *(const short8*)&KsC[row * 128 + (((kk * 4 + quad) ^ (row & 15)) * 8)];
        }
#pragma unroll
        for (int nt = 0; nt < 2; nt++) {
          sacc[0][nt] = __builtin_amdgcn_mfma_f32_16x16x32_bf16(qf[0][kk], kf[nt], sacc[0][nt], 0, 0, 0);
          sacc[1][nt] = __builtin_amdgcn_mfma_f32_16x16x32_bf16(qf[1][kk], kf[nt], sacc[1][nt], 0, 0, 0);
        }
      }
      __builtin_amdgcn_s_setprio(0);

      bool diag = (s0w + 31 > q0 + rhalf * 32);
#pragma unroll
      for (int m = 0; m < 2; m++)
#pragma unroll
        for (int r = 0; r < 4; r++) {
          int prow = m * 16 + quad * 4 + r;
          int qrow = q0 + rhalf * 32 + prow;
          float rsum = 0.f;
#pragma unroll
          for (int nt = 0; nt < 2; nt++) {
            float p = __builtin_amdgcn_exp2f(fmaf(sacc[m][nt][r], LOG2E, MBIAS));
            if (diag && (s0w + nt * 16 + l16) > qrow) p = 0.f;
            rsum += p;
            int chunk = nt * 2 + (l16 >> 3);
            PsW[prow * 64 + ((chunk ^ (prow & 7)) * 8) + (l16 & 7)] = f2bf(p);
          }
          lp[m][r] += rsum;
        }

      __builtin_amdgcn_s_setprio(1);
      short8 pf[2];
#pragma unroll
      for (int m = 0; m < 2; m++) {
        int prow = m * 16 + l16;
        pf[m] = *(const short8*)&PsW[prow * 64 + ((quad ^ (prow & 7)) * 8)];
      }
#pragma unroll
      for (int ht = 0; ht < 8; ht++) {
        int row = ht * 16 + l16;
        short8 vf = *(const short8*)&VtC[row * 64 + (((shalf * 4 + quad) ^ (row & 7)) * 8)];
        accO[0][ht] = __builtin_amdgcn_mfma_f32_16x16x32_bf16(pf[0], vf, accO[0][ht], 0, 0, 0);
        accO[1][ht] = __builtin_amdgcn_mfma_f32_16x16x32_bf16(pf[1], vf, accO[1][ht], 0, 0, 0);
      }
      __builtin_amdgcn_s_setprio(0);
    }
    __syncthreads();
  }

#pragma unroll
  for (int m = 0; m < 2; m++)
#pragma unroll
    for (int r = 0; r < 4; r++) {
#pragma unroll
      for (int d = 1; d < 16; d <<= 1) lp[m][r] += __shfl_xor(lp[m][r], d);
    }

  floatx4* xch = (floatx4*)(void*)smem;
  if (wid >= 2) {
    floatx4* dst = xch + ((wid & 1) * 1024 + lane * 16);
#pragma unroll
    for (int m = 0; m < 2; m++)
#pragma unroll
      for (int ht = 0; ht < 8; ht++)
        dst[(m * 8 + ht + lane) & 15] = accO[m][ht];
    if (l16 == 0) {
#pragma unroll
      for (int m = 0; m < 2; m++)
#pragma unroll
        for (int r = 0; r < 4; r++)
          lpbuf[(wid & 1) * 32 + m * 16 + quad * 4 + r] = lp[m][r];
    }
  }
  __syncthreads();
  if (wid < 2) {
    floatx4* src = xch + (wid * 1024 + lane * 16);
    float inv[2][4];
#pragma unroll
    for (int m = 0; m < 2; m++)
#pragma unroll
      for (int ht = 0; ht < 8; ht++)
        accO[m][ht] += src[(m * 8 + ht + lane) & 15];
#pragma unroll
    for (int m = 0; m < 2; m++)
#pragma unroll
      for (int r = 0; r < 4; r++)
        inv[m][r] = 1.0f / (lp[m][r] + lpbuf[wid * 32 + m * 16 + quad * 4 + r]);
#pragma unroll
    for (int m = 0; m < 2; m++)
#pragma unroll
      for (int ht = 0; ht < 8; ht++)
#pragma unroll
        for (int r = 0; r < 4; r++) {
          int row = q0 + wid * 32 + m * 16 + quad * 4 + r;
          att[((size_t)(b * S_ + row) * H_ + h) * HD_ + ht * 16 + l16] =
              f2bf(accO[m][ht][r] * inv[m][r]);
        }
  }
}

// ---------------------------------------------------------------------------
extern "C" void kernel_launch(void* const* d_in, const int* in_sizes, int n_in,
                              void* d_out, int out_size, void* d_ws, size_t ws_size,
                              hipStream_t stream)
{
  const float* x  = (const float*)d_in[0];   // [B,S,DM] f32
  const float* wq = (const float*)d_in[1];   // [DM, H*HD] f32
  const float* wk = (const float*)d_in[2];   // [DM, KV*HD] f32
  const float* wv = (const float*)d_in[3];   // [DM, KV*HD] f32
  const float* wo = (const float*)d_in[4];   // [H*HD, DM] f32
  const float* qs = (const float*)d_in[5];   // [HD] f32
  const float* ks = (const float*)d_in[6];   // [HD] f32

  char* ws = (char*)d_ws;
  size_t off = 0;
  u16* x_bf   = (u16*)(ws + off); off += (size_t)4096 * 2048 * 2;   // x bf16
  u16* wqkv_t = (u16*)(ws + off); off += (size_t)3072 * 2048 * 2;   // [3072][2048]
  u16* wo_t   = (u16*)(ws + off); off += (size_t)2048 * 2048 * 2;   // [2048][2048]
  u16* C1     = (u16*)(ws + off); off += (size_t)4096 * 3072 * 2;   // v bf16 (q/k regions unused)
  u16* q_rope = (u16*)(ws + off); off += (size_t)4096 * 16 * 128 * 2;
  u16* k_rope = (u16*)(ws + off); off += (size_t)4096 * 4 * 128 * 2;
  u16* vt     = (u16*)(ws + off); off += (size_t)8 * 128 * 2048 * 2;
  u16* att    = (u16*)(ws + off); off += (size_t)4096 * 2048 * 2;
  float2* rope_tab = (float2*)(ws + off); off += (size_t)2048 * 64 * 8;  // 1 MB

  // pack x + weight transposes + rope table, one launch
  k_prep<<<dim3(18944), 256, 0, stream>>>(x, wq, wk, wv, wo, x_bf, wqkv_t, wo_t, rope_tab);

  // qkv = x @ [wq|wk|wv] with fused RMSNorm+RoPE epilogue (q/k -> rope bufs)
  k_gemm_qkv<<<dim3(24, 32), 256, 0, stream>>>(x_bf, wqkv_t, qs, ks, rope_tab,
                                               C1, q_rope, k_rope);

  // v-transpose only
  k_vt<<<dim3(2048), 256, 0, stream>>>(C1, vt);

  // causal flash: 1024 blocks x 4 waves (64 q-rows/block), longest-first
  k_flash<<<dim3(1024), 256, 0, stream>>>(q_rope, k_rope, vt, att);

  // out = att @ wo  (f32 out, matching reference output dtype)
  k_gemm_bt<<<dim3(16, 32), 256, 0, stream>>>(att, wo_t, d_out, 4096, 2048, 2048, 0);

  (void)in_sizes; (void)n_in; (void)out_size; (void)ws_size;
}

// Round 6
// 273.974 us; speedup vs baseline: 1.0875x; 1.0875x over previous
//
#include <hip/hip_runtime.h>
#include <hip/hip_bf16.h>
#include <math.h>

typedef unsigned short u16;
typedef short short8 __attribute__((ext_vector_type(8)));
typedef float floatx4 __attribute__((ext_vector_type(4)));

#define B_   2
#define S_   2048
#define DM_  2048
#define H_   16
#define KVH_ 4
#define HD_  128

__device__ __forceinline__ float bf2f(u16 v) {
  union { unsigned int u; float f; } x; x.u = ((unsigned int)v) << 16; return x.f;
}
__device__ __forceinline__ u16 f2bf(float f) {
  union { float f; unsigned int u; } x; x.f = f;
  unsigned int u = x.u;
  u += 0x7FFFu + ((u >> 16) & 1u);   // RNE; inputs finite
  return (u16)(u >> 16);
}

// async 16B global->LDS (lds dest = wave-uniform base + lane*16)
#define GLDS16(gp, lp) __builtin_amdgcn_global_load_lds( \
    (const __attribute__((address_space(1))) unsigned int*)(const void*)(gp), \
    (__attribute__((address_space(3))) unsigned int*)(void*)(lp), 16, 0, 0)

// ---------------------------------------------------------------------------
// k_prep: pack_x (blocks 0..8191) + 4 weight transposes (8192..18431) +
// RoPE sincos table (18432..18943): tab[pos][fi] = (cos, sin), 1 MB.
// ---------------------------------------------------------------------------
__global__ __launch_bounds__(256) void k_prep(
    const float* __restrict__ x, const float* __restrict__ wq,
    const float* __restrict__ wk, const float* __restrict__ wv,
    const float* __restrict__ wo,
    u16* __restrict__ x_bf, u16* __restrict__ wqkv_t, u16* __restrict__ wo_t,
    float2* __restrict__ rope_tab)
{
  int bx = blockIdx.x;
  if (bx >= 18432) {                     // RoPE table: 2048 pos x 64 freq
    int idx = (bx - 18432) * 256 + threadIdx.x;
    int pos = idx >> 6;
    float fi = (float)(idx & 63);
    float ts = powf(10000.0f, fi * (1.0f / 64.0f));
    float ang = (float)pos / ts;
    rope_tab[idx] = make_float2(cosf(ang), sinf(ang));
    return;
  }
  if (bx < 8192) {                       // x -> bf16, 4 elems/thread
    int i = bx * 256 + threadIdx.x;
    const float4 v = ((const float4*)x)[i];
    u16 o[4] = { f2bf(v.x), f2bf(v.y), f2bf(v.z), f2bf(v.w) };
    *(unsigned long long*)(x_bf + (size_t)i * 4) = *(unsigned long long*)o;
    return;
  }
  bx -= 8192;
  const float* src; u16* dst; int C, cb;
  if (bx < 4096)      { src = wq; dst = wqkv_t; C = 2048; cb = 64; }
  else if (bx < 5120) { bx -= 4096; src = wk; dst = wqkv_t + (size_t)2048 * 2048; C = 512; cb = 16; }
  else if (bx < 6144) { bx -= 5120; src = wv; dst = wqkv_t + (size_t)2560 * 2048; C = 512; cb = 16; }
  else                { bx -= 6144; src = wo; dst = wo_t; C = 2048; cb = 64; }
  const int R = 2048;
  int c0 = (bx % cb) * 32, r0 = (bx / cb) * 32;
  __shared__ float tile[32][33];
  int tx = threadIdx.x & 31, ty = threadIdx.x >> 5;
#pragma unroll
  for (int j = 0; j < 4; j++)
    tile[ty * 4 + j][tx] = src[(size_t)(r0 + ty * 4 + j) * C + c0 + tx];
  __syncthreads();
#pragma unroll
  for (int j = 0; j < 4; j++)
    dst[(size_t)(c0 + ty * 4 + j) * R + r0 + tx] = f2bf(tile[tx][ty * 4 + j]);
}

// ---------------------------------------------------------------------------
// GEMM (generic, used for att@wo): C[M][N] = A[M][K]*Bt[N][K]^T, f32/bf16 out
// 128x128 tile, BK=64, GLDS staging, chunk^(row&7) swizzle.
// ---------------------------------------------------------------------------
__global__ __launch_bounds__(256, 3) void k_gemm_bt(
    const u16* __restrict__ A, const u16* __restrict__ Bt,
    void* __restrict__ Cout, int M, int N, int K, int c_bf16)
{
  __shared__ u16 As[128 * 64];
  __shared__ u16 Bs[128 * 64];
  int tid = threadIdx.x;
  int lane = tid & 63;
  int quad = lane >> 4, l16 = lane & 15;
  int wid = tid >> 6;
  int m0 = blockIdx.y * 128, n0 = blockIdx.x * 128;
  int wm = (wid >> 1) * 64, wn = (wid & 1) * 64;

  floatx4 acc[4][4] = {};

  int srow = tid >> 3;
  int gjc0 = (tid & 7) ^ (srow & 7);
  const u16* Ap = A + (size_t)(m0 + srow) * K + gjc0 * 8;
  const u16* Bp = Bt + (size_t)(n0 + srow) * K + gjc0 * 8;
  u16* AsW = As + tid * 8;
  u16* BsW = Bs + tid * 8;

  for (int kt = 0; kt < K; kt += 64) {
    __syncthreads();
#pragma unroll
    for (int j = 0; j < 4; j++) {
      GLDS16(Ap + (size_t)(j * 32) * K, AsW + j * 2048);
      GLDS16(Bp + (size_t)(j * 32) * K, BsW + j * 2048);
    }
    Ap += 64; Bp += 64;
    __syncthreads();

#pragma unroll
    for (int ks = 0; ks < 2; ks++) {
      short8 af[4], bfv[4];
#pragma unroll
      for (int mi = 0; mi < 4; mi++) {
        int row = wm + mi * 16 + l16;
        af[mi] = *(const short8*)&As[row * 64 + (((ks * 4 + quad) ^ (row & 7)) * 8)];
      }
#pragma unroll
      for (int ni = 0; ni < 4; ni++) {
        int row = wn + ni * 16 + l16;
        bfv[ni] = *(const short8*)&Bs[row * 64 + (((ks * 4 + quad) ^ (row & 7)) * 8)];
      }
#pragma unroll
      for (int mi = 0; mi < 4; mi++)
#pragma unroll
        for (int ni = 0; ni < 4; ni++)
          acc[mi][ni] = __builtin_amdgcn_mfma_f32_16x16x32_bf16(
              af[mi], bfv[ni], acc[mi][ni], 0, 0, 0);
    }
  }

#pragma unroll
  for (int mi = 0; mi < 4; mi++)
#pragma unroll
    for (int ni = 0; ni < 4; ni++)
#pragma unroll
      for (int r = 0; r < 4; r++) {
        int row = m0 + wm + mi * 16 + quad * 4 + r;
        int col = n0 + wn + ni * 16 + l16;
        float v = acc[mi][ni][r];
        if (c_bf16) ((u16*)Cout)[(size_t)row * N + col] = f2bf(v);
        else        ((float*)Cout)[(size_t)row * N + col] = v;
      }
}

// ---------------------------------------------------------------------------
// k_gemm_qkv: x_bf @ [wq|wk|wv]^T with FUSED epilogues:
//   q/k heads (nt 0..19): RMSNorm + RoPE (table sincos) -> qr / kr
//   v heads  (nt 20..23): in-LDS transpose -> vt DIRECTLY (C1 + k_vt gone:
//     -32 MB HBM round-trip, -1 kernel launch vs round 5).
// v-transpose layout: T[hd 128][s 128] bf16, 8-u16 chunks, slot = c^(hd&7);
// scalar stores <=4-way conflict (v-blocks only), b128 reads uniform 8/bank
// (optimal), global stores 256B-contiguous per 16 lanes.
// ---------------------------------------------------------------------------
__global__ __launch_bounds__(256, 3) void k_gemm_qkv(
    const u16* __restrict__ A, const u16* __restrict__ Bt,
    const float* __restrict__ qs, const float* __restrict__ ks,
    const float2* __restrict__ tab,
    u16* __restrict__ qr, u16* __restrict__ kr, u16* __restrict__ vt)
{
  const int K = 2048;
  __shared__ u16 smem[16384] __attribute__((aligned(16)));   // 32 KB
  u16* As = smem;
  u16* Bs = smem + 8192;
  float* exch = (float*)smem;        // q/k epilogue overlay: [16][256] f32

  int tid = threadIdx.x;
  int lane = tid & 63;
  int quad = lane >> 4, l16 = lane & 15;
  int wid = tid >> 6;
  int m0 = blockIdx.y * 128, n0 = blockIdx.x * 128;
  int wm = (wid >> 1) * 64, wn = (wid & 1) * 64;

  floatx4 acc[4][4] = {};

  int srow = tid >> 3;
  int gjc0 = (tid & 7) ^ (srow & 7);
  const u16* Ap = A + (size_t)(m0 + srow) * K + gjc0 * 8;
  const u16* Bp = Bt + (size_t)(n0 + srow) * K + gjc0 * 8;
  u16* AsW = As + tid * 8;
  u16* BsW = Bs + tid * 8;

  for (int kt = 0; kt < K; kt += 64) {
    __syncthreads();
#pragma unroll
    for (int j = 0; j < 4; j++) {
      GLDS16(Ap + (size_t)(j * 32) * K, AsW + j * 2048);
      GLDS16(Bp + (size_t)(j * 32) * K, BsW + j * 2048);
    }
    Ap += 64; Bp += 64;
    __syncthreads();

#pragma unroll
    for (int ks = 0; ks < 2; ks++) {
      short8 af[4], bfv[4];
#pragma unroll
      for (int mi = 0; mi < 4; mi++) {
        int row = wm + mi * 16 + l16;
        af[mi] = *(const short8*)&As[row * 64 + (((ks * 4 + quad) ^ (row & 7)) * 8)];
      }
#pragma unroll
      for (int ni = 0; ni < 4; ni++) {
        int row = wn + ni * 16 + l16;
        bfv[ni] = *(const short8*)&Bs[row * 64 + (((ks * 4 + quad) ^ (row & 7)) * 8)];
      }
#pragma unroll
      for (int mi = 0; mi < 4; mi++)
#pragma unroll
        for (int ni = 0; ni < 4; ni++)
          acc[mi][ni] = __builtin_amdgcn_mfma_f32_16x16x32_bf16(
              af[mi], bfv[ni], acc[mi][ni], 0, 0, 0);
    }
  }

  int nt = blockIdx.x;               // head index (q: 0..15, k: 16..19, v: 20..23)
  if (nt >= 20) {                    // ---- v-tiles: LDS transpose -> vt ----
    int kv = nt - 20;
    int b  = m0 >> 11;               // row space = b*S + s
    int s0 = m0 & (S_ - 1);
    __syncthreads();                 // K-loop LDS reads done before overwrite
#pragma unroll
    for (int mi = 0; mi < 4; mi++)
#pragma unroll
      for (int ni = 0; ni < 4; ni++)
#pragma unroll
        for (int r = 0; r < 4; r++) {
          int sl  = wm + mi * 16 + quad * 4 + r;   // s_local (tile row)
          int col = wn + ni * 16 + l16;            // hd      (tile col)
          smem[col * 128 + (((sl >> 3) ^ (col & 7)) * 8) + (sl & 7)] =
              f2bf(acc[mi][ni][r]);
        }
    __syncthreads();
    size_t vbase = ((size_t)(b * KVH_ + kv) * HD_) * S_ + s0;
#pragma unroll
    for (int i = 0; i < 8; i++) {
      int flat = i * 256 + tid;
      int hd = flat >> 4, sc = flat & 15;          // 16 lanes -> 256B contig
      short8 vv = *(const short8*)&smem[hd * 128 + ((sc ^ (hd & 7)) * 8)];
      *(short8*)(vt + vbase + (size_t)hd * S_ + sc * 8) = vv;
    }
    return;
  }

  // ---- q/k heads: fused RMSNorm + RoPE epilogue ----
  bool isq = nt < 16;
  const float* scp = isq ? qs : ks;
  float sc_own[4], sc_par[4];
#pragma unroll
  for (int ni = 0; ni < 4; ni++) {
    sc_own[ni] = scp[wn + ni * 16 + l16];
    sc_par[ni] = scp[(wn ^ 64) + ni * 16 + l16];
  }
  float ssign = (wn == 0) ? -1.0f : 1.0f;   // d<64: y*c - p*s ; d>=64: y*c + p*s

#pragma unroll
  for (int mi = 0; mi < 4; mi++) {
    __syncthreads();                 // prior round's reads (or K-loop) done
#pragma unroll
    for (int ni = 0; ni < 4; ni++)
#pragma unroll
      for (int r = 0; r < 4; r++)
        exch[(ni * 4 + r) * 256 + wid * 64 + lane] = acc[mi][ni][r];
    __syncthreads();
    float part[4][4];
#pragma unroll
    for (int ni = 0; ni < 4; ni++)
#pragma unroll
      for (int r = 0; r < 4; r++)
        part[ni][r] = exch[(ni * 4 + r) * 256 + (wid ^ 1) * 64 + lane];

#pragma unroll
    for (int r = 0; r < 4; r++) {
      float ss = 0.f;
#pragma unroll
      for (int ni = 0; ni < 4; ni++)
        ss += acc[mi][ni][r] * acc[mi][ni][r] + part[ni][r] * part[ni][r];
#pragma unroll
      for (int d = 1; d < 16; d <<= 1) ss += __shfl_xor(ss, d);
      float rs = rsqrtf(ss * (1.0f / 128.0f) + 1e-6f);
      int row = m0 + wm + mi * 16 + quad * 4 + r;
      int pos = row & (S_ - 1);
#pragma unroll
      for (int ni = 0; ni < 4; ni++) {
        float2 cs = tab[pos * 64 + ni * 16 + l16];
        float yo = acc[mi][ni][r] * rs * sc_own[ni];
        float yp = part[ni][r] * rs * sc_par[ni];
        float o = fmaf(ssign * yp, cs.y, yo * cs.x);
        if (isq) o *= 0.088388347648318447f;
        int d = wn + ni * 16 + l16;
        if (isq) qr[((size_t)row * H_ + nt) * HD_ + d] = f2bf(o);
        else     kr[((size_t)row * KVH_ + (nt - 16)) * HD_ + d] = f2bf(o);
      }
    }
  }
}

// ---------------------------------------------------------------------------
// Flash attention v5 (unchanged: zero bank conflicts):
// 1024 blocks x 4 waves, 64 q-rows/block, waves split (row-half, s-half),
// GLDS double-buffered K/V, Ps [32][64] chunk^(prow&7), rotated epilogue
// exchange.  FIXED-MAX softmax (|score| <= 11.32 post-RMSNorm).
// ---------------------------------------------------------------------------
__global__ __launch_bounds__(256, 2) void k_flash(
    const u16* __restrict__ qr, const u16* __restrict__ kr,
    const u16* __restrict__ vt, u16* __restrict__ att)
{
  __shared__ u16 smem[40960] __attribute__((aligned(16)));
  u16* Ps = smem + 32768;
  float* lpbuf = (float*)(smem + 32768);   // overlays Ps (dead in epilogue)

  int tid = threadIdx.x, lane = tid & 63, wid = tid >> 6;
  int quad = lane >> 4, l16 = lane & 15;
  int rhalf = wid & 1;
  int shalf = wid >> 1;
  int bx = blockIdx.x;
  int it = 31 - (bx >> 5);
  int hb = bx & 31;
  int h = hb & 15, b = hb >> 4;
  int kvh = h >> 2;
  int q0 = it * 64;
  int NT = it + 1;

  short8 qf[2][4];
#pragma unroll
  for (int m = 0; m < 2; m++) {
    const u16* qb = qr + ((size_t)(b * S_ + q0 + rhalf * 32 + m * 16 + l16) * H_ + h) * HD_;
#pragma unroll
    for (int kk = 0; kk < 4; kk++)
      qf[m][kk] = *(const short8*)(qb + kk * 32 + quad * 8);
  }

  int gjk = (tid & 15) ^ ((tid >> 4) & 15);
  int gjv = (tid & 7) ^ ((tid >> 3) & 7);
  const u16* kp = kr + ((size_t)(b * S_ + (tid >> 4)) * KVH_ + kvh) * HD_ + gjk * 8;
  const u16* vp = vt + ((size_t)(b * KVH_ + kvh) * HD_ + (tid >> 3)) * S_ + gjv * 8;

#pragma unroll
  for (int j = 0; j < 4; j++) {
    GLDS16(kp + (size_t)(j * 16) * KVH_ * HD_, smem + (size_t)(j * 256 + tid) * 8);
    GLDS16(vp + (size_t)(j * 32) * S_,         smem + 16384 + (size_t)(j * 256 + tid) * 8);
  }
  kp += (size_t)64 * KVH_ * HD_;
  vp += 64;
  __syncthreads();

  floatx4 accO[2][8] = {};
  float lp[2][4] = {};
  u16* PsW = Ps + wid * 2048;

  const float LOG2E = 1.4426950408889634f;
  const float MBIAS = -12.5f * 1.4426950408889634f;
  int qmax = q0 + rhalf * 32 + 31;

  for (int kt = 0; kt < NT; kt++) {
    if (kt + 1 < NT) {
      u16* KD = smem + (size_t)((kt + 1) & 1) * 8192;
      u16* VD = smem + 16384 + (size_t)((kt + 1) & 1) * 8192;
#pragma unroll
      for (int j = 0; j < 4; j++) {
        GLDS16(kp + (size_t)(j * 16) * KVH_ * HD_, KD + (size_t)(j * 256 + tid) * 8);
        GLDS16(vp + (size_t)(j * 32) * S_,         VD + (size_t)(j * 256 + tid) * 8);
      }
      kp += (size_t)64 * KVH_ * HD_;
      vp += 64;
    }

    int k0 = kt * 64;
    int s0w = k0 + shalf * 32;
    if (s0w <= qmax) {
      const u16* KsC = smem + (size_t)(kt & 1) * 8192;
      const u16* VtC = smem + 16384 + (size_t)(kt & 1) * 8192;

      floatx4 sacc[2][2] = {};
      __builtin_amdgcn_s_setprio(1);
#pragma unroll
      for (int kk = 0; kk < 4; kk++) {
        short8 kf[2];
#pragma unroll
        for (int nt = 0; nt < 2; nt++) {
          int row = shalf * 32 + nt * 16 + l16;
          kf[nt] = *(const short8*)&KsC[row * 128 + (((kk * 4 + quad) ^ (row & 15)) * 8)];
        }
#pragma unroll
        for (int nt = 0; nt < 2; nt++) {
          sacc[0][nt] = __builtin_amdgcn_mfma_f32_16x16x32_bf16(qf[0][kk], kf[nt], sacc[0][nt], 0, 0, 0);
          sacc[1][nt] = __builtin_amdgcn_mfma_f32_16x16x32_bf16(qf[1][kk], kf[nt], sacc[1][nt], 0, 0, 0);
        }
      }
      __builtin_amdgcn_s_setprio(0);

      bool diag = (s0w + 31 > q0 + rhalf * 32);
#pragma unroll
      for (int m = 0; m < 2; m++)
#pragma unroll
        for (int r = 0; r < 4; r++) {
          int prow = m * 16 + quad * 4 + r;
          int qrow = q0 + rhalf * 32 + prow;
          float rsum = 0.f;
#pragma unroll
          for (int nt = 0; nt < 2; nt++) {
            float p = __builtin_amdgcn_exp2f(fmaf(sacc[m][nt][r], LOG2E, MBIAS));
            if (diag && (s0w + nt * 16 + l16) > qrow) p = 0.f;
            rsum += p;
            int chunk = nt * 2 + (l16 >> 3);
            PsW[prow * 64 + ((chunk ^ (prow & 7)) * 8) + (l16 & 7)] = f2bf(p);
          }
          lp[m][r] += rsum;
        }

      __builtin_amdgcn_s_setprio(1);
      short8 pf[2];
#pragma unroll
      for (int m = 0; m < 2; m++) {
        int prow = m * 16 + l16;
        pf[m] = *(const short8*)&PsW[prow * 64 + ((quad ^ (prow & 7)) * 8)];
      }
#pragma unroll
      for (int ht = 0; ht < 8; ht++) {
        int row = ht * 16 + l16;
        short8 vf = *(const short8*)&VtC[row * 64 + (((shalf * 4 + quad) ^ (row & 7)) * 8)];
        accO[0][ht] = __builtin_amdgcn_mfma_f32_16x16x32_bf16(pf[0], vf, accO[0][ht], 0, 0, 0);
        accO[1][ht] = __builtin_amdgcn_mfma_f32_16x16x32_bf16(pf[1], vf, accO[1][ht], 0, 0, 0);
      }
      __builtin_amdgcn_s_setprio(0);
    }
    __syncthreads();
  }

#pragma unroll
  for (int m = 0; m < 2; m++)
#pragma unroll
    for (int r = 0; r < 4; r++) {
#pragma unroll
      for (int d = 1; d < 16; d <<= 1) lp[m][r] += __shfl_xor(lp[m][r], d);
    }

  floatx4* xch = (floatx4*)(void*)smem;
  if (wid >= 2) {
    floatx4* dst = xch + ((wid & 1) * 1024 + lane * 16);
#pragma unroll
    for (int m = 0; m < 2; m++)
#pragma unroll
      for (int ht = 0; ht < 8; ht++)
        dst[(m * 8 + ht + lane) & 15] = accO[m][ht];
    if (l16 == 0) {
#pragma unroll
      for (int m = 0; m < 2; m++)
#pragma unroll
        for (int r = 0; r < 4; r++)
          lpbuf[(wid & 1) * 32 + m * 16 + quad * 4 + r] = lp[m][r];
    }
  }
  __syncthreads();
  if (wid < 2) {
    floatx4* src = xch + (wid * 1024 + lane * 16);
    float inv[2][4];
#pragma unroll
    for (int m = 0; m < 2; m++)
#pragma unroll
      for (int ht = 0; ht < 8; ht++)
        accO[m][ht] += src[(m * 8 + ht + lane) & 15];
#pragma unroll
    for (int m = 0; m < 2; m++)
#pragma unroll
      for (int r = 0; r < 4; r++)
        inv[m][r] = 1.0f / (lp[m][r] + lpbuf[wid * 32 + m * 16 + quad * 4 + r]);
#pragma unroll
    for (int m = 0; m < 2; m++)
#pragma unroll
      for (int ht = 0; ht < 8; ht++)
#pragma unroll
        for (int r = 0; r < 4; r++) {
          int row = q0 + wid * 32 + m * 16 + quad * 4 + r;
          att[((size_t)(b * S_ + row) * H_ + h) * HD_ + ht * 16 + l16] =
              f2bf(accO[m][ht][r] * inv[m][r]);
        }
  }
}

// ---------------------------------------------------------------------------
extern "C" void kernel_launch(void* const* d_in, const int* in_sizes, int n_in,
                              void* d_out, int out_size, void* d_ws, size_t ws_size,
                              hipStream_t stream)
{
  const float* x  = (const float*)d_in[0];   // [B,S,DM] f32
  const float* wq = (const float*)d_in[1];   // [DM, H*HD] f32
  const float* wk = (const float*)d_in[2];   // [DM, KV*HD] f32
  const float* wv = (const float*)d_in[3];   // [DM, KV*HD] f32
  const float* wo = (const float*)d_in[4];   // [H*HD, DM] f32
  const float* qs = (const float*)d_in[5];   // [HD] f32
  const float* ks = (const float*)d_in[6];   // [HD] f32

  char* ws = (char*)d_ws;
  size_t off = 0;
  u16* x_bf   = (u16*)(ws + off); off += (size_t)4096 * 2048 * 2;   // x bf16
  u16* wqkv_t = (u16*)(ws + off); off += (size_t)3072 * 2048 * 2;   // [3072][2048]
  u16* wo_t   = (u16*)(ws + off); off += (size_t)2048 * 2048 * 2;   // [2048][2048]
  u16* q_rope = (u16*)(ws + off); off += (size_t)4096 * 16 * 128 * 2;
  u16* k_rope = (u16*)(ws + off); off += (size_t)4096 * 4 * 128 * 2;
  u16* vt     = (u16*)(ws + off); off += (size_t)8 * 128 * 2048 * 2;
  u16* att    = (u16*)(ws + off); off += (size_t)4096 * 2048 * 2;
  float2* rope_tab = (float2*)(ws + off); off += (size_t)2048 * 64 * 8;  // 1 MB

  // pack x + weight transposes + rope table, one launch
  k_prep<<<dim3(18944), 256, 0, stream>>>(x, wq, wk, wv, wo, x_bf, wqkv_t, wo_t, rope_tab);

  // qkv = x @ [wq|wk|wv]; fused RMSNorm+RoPE (q/k) and v-transpose (v)
  k_gemm_qkv<<<dim3(24, 32), 256, 0, stream>>>(x_bf, wqkv_t, qs, ks, rope_tab,
                                               q_rope, k_rope, vt);

  // causal flash: 1024 blocks x 4 waves (64 q-rows/block), longest-first
  k_flash<<<dim3(1024), 256, 0, stream>>>(q_rope, k_rope, vt, att);

  // out = att @ wo  (f32 out, matching reference output dtype)
  k_gemm_bt<<<dim3(16, 32), 256, 0, stream>>>(att, wo_t, d_out, 4096, 2048, 2048, 0);

  (void)in_sizes; (void)n_in; (void)out_size; (void)ws_size;
}

// Round 8
// 265.042 us; speedup vs baseline: 1.1242x; 1.0337x over previous
//
#include <hip/hip_runtime.h>
#include <hip/hip_bf16.h>
#include <math.h>

typedef unsigned short u16;
typedef short short8 __attribute__((ext_vector_type(8)));
typedef float floatx4 __attribute__((ext_vector_type(4)));

#define B_   2
#define S_   2048
#define DM_  2048
#define H_   16
#define KVH_ 4
#define HD_  128

__device__ __forceinline__ float bf2f(u16 v) {
  union { unsigned int u; float f; } x; x.u = ((unsigned int)v) << 16; return x.f;
}
__device__ __forceinline__ u16 f2bf(float f) {
  union { float f; unsigned int u; } x; x.f = f;
  unsigned int u = x.u;
  u += 0x7FFFu + ((u >> 16) & 1u);   // RNE; inputs finite
  return (u16)(u >> 16);
}

// async 16B global->LDS (lds dest = wave-uniform base + lane*16)
#define GLDS16(gp, lp) __builtin_amdgcn_global_load_lds( \
    (const __attribute__((address_space(1))) unsigned int*)(const void*)(gp), \
    (__attribute__((address_space(3))) unsigned int*)(void*)(lp), 16, 0, 0)

// ---------------------------------------------------------------------------
// k_prep: pack_x (blocks 0..8191) + 4 weight transposes (8192..18431) +
// RoPE sincos table (18432..18943): tab[pos][fi] = (cos, sin), 1 MB.
// ---------------------------------------------------------------------------
__global__ __launch_bounds__(256) void k_prep(
    const float* __restrict__ x, const float* __restrict__ wq,
    const float* __restrict__ wk, const float* __restrict__ wv,
    const float* __restrict__ wo,
    u16* __restrict__ x_bf, u16* __restrict__ wqkv_t, u16* __restrict__ wo_t,
    float2* __restrict__ rope_tab)
{
  int bx = blockIdx.x;
  if (bx >= 18432) {                     // RoPE table: 2048 pos x 64 freq
    int idx = (bx - 18432) * 256 + threadIdx.x;
    int pos = idx >> 6;
    float fi = (float)(idx & 63);
    float ts = powf(10000.0f, fi * (1.0f / 64.0f));
    float ang = (float)pos / ts;
    rope_tab[idx] = make_float2(cosf(ang), sinf(ang));
    return;
  }
  if (bx < 8192) {                       // x -> bf16, 4 elems/thread
    int i = bx * 256 + threadIdx.x;
    const float4 v = ((const float4*)x)[i];
    u16 o[4] = { f2bf(v.x), f2bf(v.y), f2bf(v.z), f2bf(v.w) };
    *(unsigned long long*)(x_bf + (size_t)i * 4) = *(unsigned long long*)o;
    return;
  }
  bx -= 8192;
  const float* src; u16* dst; int C, cb;
  if (bx < 4096)      { src = wq; dst = wqkv_t; C = 2048; cb = 64; }
  else if (bx < 5120) { bx -= 4096; src = wk; dst = wqkv_t + (size_t)2048 * 2048; C = 512; cb = 16; }
  else if (bx < 6144) { bx -= 5120; src = wv; dst = wqkv_t + (size_t)2560 * 2048; C = 512; cb = 16; }
  else                { bx -= 6144; src = wo; dst = wo_t; C = 2048; cb = 64; }
  const int R = 2048;
  int c0 = (bx % cb) * 32, r0 = (bx / cb) * 32;
  __shared__ float tile[32][33];
  int tx = threadIdx.x & 31, ty = threadIdx.x >> 5;
#pragma unroll
  for (int j = 0; j < 4; j++)
    tile[ty * 4 + j][tx] = src[(size_t)(r0 + ty * 4 + j) * C + c0 + tx];
  __syncthreads();
#pragma unroll
  for (int j = 0; j < 4; j++)
    dst[(size_t)(c0 + ty * 4 + j) * R + r0 + tx] = f2bf(tile[tx][ty * 4 + j]);
}

// ---------------------------------------------------------------------------
// GEMM (generic, used for att@wo): C[M][N] = A[M][K]*Bt[N][K]^T, f32/bf16 out
// 128x128 tile, BK=64, GLDS staging, chunk^(row&7) swizzle.
// ---------------------------------------------------------------------------
__global__ __launch_bounds__(256, 3) void k_gemm_bt(
    const u16* __restrict__ A, const u16* __restrict__ Bt,
    void* __restrict__ Cout, int M, int N, int K, int c_bf16)
{
  __shared__ u16 As[128 * 64];
  __shared__ u16 Bs[128 * 64];
  int tid = threadIdx.x;
  int lane = tid & 63;
  int quad = lane >> 4, l16 = lane & 15;
  int wid = tid >> 6;
  int m0 = blockIdx.y * 128, n0 = blockIdx.x * 128;
  int wm = (wid >> 1) * 64, wn = (wid & 1) * 64;

  floatx4 acc[4][4] = {};

  int srow = tid >> 3;
  int gjc0 = (tid & 7) ^ (srow & 7);
  const u16* Ap = A + (size_t)(m0 + srow) * K + gjc0 * 8;
  const u16* Bp = Bt + (size_t)(n0 + srow) * K + gjc0 * 8;
  u16* AsW = As + tid * 8;
  u16* BsW = Bs + tid * 8;

  for (int kt = 0; kt < K; kt += 64) {
    __syncthreads();
#pragma unroll
    for (int j = 0; j < 4; j++) {
      GLDS16(Ap + (size_t)(j * 32) * K, AsW + j * 2048);
      GLDS16(Bp + (size_t)(j * 32) * K, BsW + j * 2048);
    }
    Ap += 64; Bp += 64;
    __syncthreads();

#pragma unroll
    for (int ks = 0; ks < 2; ks++) {
      short8 af[4], bfv[4];
#pragma unroll
      for (int mi = 0; mi < 4; mi++) {
        int row = wm + mi * 16 + l16;
        af[mi] = *(const short8*)&As[row * 64 + (((ks * 4 + quad) ^ (row & 7)) * 8)];
      }
#pragma unroll
      for (int ni = 0; ni < 4; ni++) {
        int row = wn + ni * 16 + l16;
        bfv[ni] = *(const short8*)&Bs[row * 64 + (((ks * 4 + quad) ^ (row & 7)) * 8)];
      }
#pragma unroll
      for (int mi = 0; mi < 4; mi++)
#pragma unroll
        for (int ni = 0; ni < 4; ni++)
          acc[mi][ni] = __builtin_amdgcn_mfma_f32_16x16x32_bf16(
              af[mi], bfv[ni], acc[mi][ni], 0, 0, 0);
    }
  }

#pragma unroll
  for (int mi = 0; mi < 4; mi++)
#pragma unroll
    for (int ni = 0; ni < 4; ni++)
#pragma unroll
      for (int r = 0; r < 4; r++) {
        int row = m0 + wm + mi * 16 + quad * 4 + r;
        int col = n0 + wn + ni * 16 + l16;
        float v = acc[mi][ni][r];
        if (c_bf16) ((u16*)Cout)[(size_t)row * N + col] = f2bf(v);
        else        ((float*)Cout)[(size_t)row * N + col] = v;
      }
}

// ---------------------------------------------------------------------------
// k_gemm_qkv: x_bf @ [wq|wk|wv]^T with FUSED epilogues:
//   q/k heads (nt 0..19): RMSNorm + RoPE (table sincos) -> qr / kr
//   v heads  (nt 20..23): in-LDS transpose -> vt directly.
// ---------------------------------------------------------------------------
__global__ __launch_bounds__(256, 3) void k_gemm_qkv(
    const u16* __restrict__ A, const u16* __restrict__ Bt,
    const float* __restrict__ qs, const float* __restrict__ ks,
    const float2* __restrict__ tab,
    u16* __restrict__ qr, u16* __restrict__ kr, u16* __restrict__ vt)
{
  const int K = 2048;
  __shared__ u16 smem[16384] __attribute__((aligned(16)));   // 32 KB
  u16* As = smem;
  u16* Bs = smem + 8192;
  float* exch = (float*)smem;        // q/k epilogue overlay: [16][256] f32

  int tid = threadIdx.x;
  int lane = tid & 63;
  int quad = lane >> 4, l16 = lane & 15;
  int wid = tid >> 6;
  int m0 = blockIdx.y * 128, n0 = blockIdx.x * 128;
  int wm = (wid >> 1) * 64, wn = (wid & 1) * 64;

  floatx4 acc[4][4] = {};

  int srow = tid >> 3;
  int gjc0 = (tid & 7) ^ (srow & 7);
  const u16* Ap = A + (size_t)(m0 + srow) * K + gjc0 * 8;
  const u16* Bp = Bt + (size_t)(n0 + srow) * K + gjc0 * 8;
  u16* AsW = As + tid * 8;
  u16* BsW = Bs + tid * 8;

  for (int kt = 0; kt < K; kt += 64) {
    __syncthreads();
#pragma unroll
    for (int j = 0; j < 4; j++) {
      GLDS16(Ap + (size_t)(j * 32) * K, AsW + j * 2048);
      GLDS16(Bp + (size_t)(j * 32) * K, BsW + j * 2048);
    }
    Ap += 64; Bp += 64;
    __syncthreads();

#pragma unroll
    for (int ks = 0; ks < 2; ks++) {
      short8 af[4], bfv[4];
#pragma unroll
      for (int mi = 0; mi < 4; mi++) {
        int row = wm + mi * 16 + l16;
        af[mi] = *(const short8*)&As[row * 64 + (((ks * 4 + quad) ^ (row & 7)) * 8)];
      }
#pragma unroll
      for (int ni = 0; ni < 4; ni++) {
        int row = wn + ni * 16 + l16;
        bfv[ni] = *(const short8*)&Bs[row * 64 + (((ks * 4 + quad) ^ (row & 7)) * 8)];
      }
#pragma unroll
      for (int mi = 0; mi < 4; mi++)
#pragma unroll
        for (int ni = 0; ni < 4; ni++)
          acc[mi][ni] = __builtin_amdgcn_mfma_f32_16x16x32_bf16(
              af[mi], bfv[ni], acc[mi][ni], 0, 0, 0);
    }
  }

  int nt = blockIdx.x;               // head index (q: 0..15, k: 16..19, v: 20..23)
  if (nt >= 20) {                    // ---- v-tiles: LDS transpose -> vt ----
    int kv = nt - 20;
    int b  = m0 >> 11;               // row space = b*S + s
    int s0 = m0 & (S_ - 1);
    __syncthreads();                 // K-loop LDS reads done before overwrite
#pragma unroll
    for (int mi = 0; mi < 4; mi++)
#pragma unroll
      for (int ni = 0; ni < 4; ni++)
#pragma unroll
        for (int r = 0; r < 4; r++) {
          int sl  = wm + mi * 16 + quad * 4 + r;   // s_local (tile row)
          int col = wn + ni * 16 + l16;            // hd      (tile col)
          smem[col * 128 + (((sl >> 3) ^ (col & 7)) * 8) + (sl & 7)] =
              f2bf(acc[mi][ni][r]);
        }
    __syncthreads();
    size_t vbase = ((size_t)(b * KVH_ + kv) * HD_) * S_ + s0;
#pragma unroll
    for (int i = 0; i < 8; i++) {
      int flat = i * 256 + tid;
      int hd = flat >> 4, sc = flat & 15;          // 16 lanes -> 256B contig
      short8 vv = *(const short8*)&smem[hd * 128 + ((sc ^ (hd & 7)) * 8)];
      *(short8*)(vt + vbase + (size_t)hd * S_ + sc * 8) = vv;
    }
    return;
  }

  // ---- q/k heads: fused RMSNorm + RoPE epilogue ----
  bool isq = nt < 16;
  const float* scp = isq ? qs : ks;
  float sc_own[4], sc_par[4];
#pragma unroll
  for (int ni = 0; ni < 4; ni++) {
    sc_own[ni] = scp[wn + ni * 16 + l16];
    sc_par[ni] = scp[(wn ^ 64) + ni * 16 + l16];
  }
  float ssign = (wn == 0) ? -1.0f : 1.0f;   // d<64: y*c - p*s ; d>=64: y*c + p*s

#pragma unroll
  for (int mi = 0; mi < 4; mi++) {
    __syncthreads();                 // prior round's reads (or K-loop) done
#pragma unroll
    for (int ni = 0; ni < 4; ni++)
#pragma unroll
      for (int r = 0; r < 4; r++)
        exch[(ni * 4 + r) * 256 + wid * 64 + lane] = acc[mi][ni][r];
    __syncthreads();
    float part[4][4];
#pragma unroll
    for (int ni = 0; ni < 4; ni++)
#pragma unroll
      for (int r = 0; r < 4; r++)
        part[ni][r] = exch[(ni * 4 + r) * 256 + (wid ^ 1) * 64 + lane];

#pragma unroll
    for (int r = 0; r < 4; r++) {
      float ss = 0.f;
#pragma unroll
      for (int ni = 0; ni < 4; ni++)
        ss += acc[mi][ni][r] * acc[mi][ni][r] + part[ni][r] * part[ni][r];
#pragma unroll
      for (int d = 1; d < 16; d <<= 1) ss += __shfl_xor(ss, d);
      float rs = rsqrtf(ss * (1.0f / 128.0f) + 1e-6f);
      int row = m0 + wm + mi * 16 + quad * 4 + r;
      int pos = row & (S_ - 1);
#pragma unroll
      for (int ni = 0; ni < 4; ni++) {
        float2 cs = tab[pos * 64 + ni * 16 + l16];
        float yo = acc[mi][ni][r] * rs * sc_own[ni];
        float yp = part[ni][r] * rs * sc_par[ni];
        float o = fmaf(ssign * yp, cs.y, yo * cs.x);
        if (isq) o *= 0.088388347648318447f;
        int d = wn + ni * 16 + l16;
        if (isq) qr[((size_t)row * H_ + nt) * HD_ + d] = f2bf(o);
        else     kr[((size_t)row * KVH_ + (nt - 16)) * HD_ + d] = f2bf(o);
      }
    }
  }
}

// ---------------------------------------------------------------------------
// Flash attention v6: IN-REGISTER P path (T12-style).
//   - QK^T operand-swapped: mfma(K, Q) -> sacc row = stored kcol (quad*4+r),
//     col = qrow (l16).
//   - K staged with PERMUTED source rows: stored row R=R0+16j holds actual
//     row base + (j&1)*4 + (j>>1)*32, base = (R0>>2)*8 + (R0&3).  With this
//     bijection each lane's 8 scores are exactly the PV A-frag k-slots
//     (actual kcol = 8*quad + 4*nt + r), so P never touches LDS:
//     8 v_cvt_pk_bf16_f32 replace 16 f2bf + 16 ds_write + 2 ds_read_b128.
//   - Ps buffer gone: LDS 80 -> 64 KB.  lp is per-lane; two shfl_xor (16,32)
//     at the end recover full row sums.
// 1024 blocks x 4 waves, 64 q-rows/block, waves split (row-half, s-half);
// GLDS double-buffered K/V, 1 barrier per kv-tile.
// FIXED-MAX softmax (Cauchy-Schwarz bound |score| <= 11.32 post-RMSNorm).
// ---------------------------------------------------------------------------
__global__ __launch_bounds__(256, 2) void k_flash(
    const u16* __restrict__ qr, const u16* __restrict__ kr,
    const u16* __restrict__ vt, u16* __restrict__ att)
{
  // LDS 64 KB (u16 units): K dbuf 2x8192 @0, V dbuf 2x8192 @16384
  __shared__ u16 smem[32768] __attribute__((aligned(16)));
  float* lpbuf = (float*)(smem + 16384);   // epilogue overlay on V region

  int tid = threadIdx.x, lane = tid & 63, wid = tid >> 6;
  int quad = lane >> 4, l16 = lane & 15;
  int rhalf = wid & 1;               // q-row half
  int shalf = wid >> 1;              // s-col half of each kv tile
  int bx = blockIdx.x;
  int it = 31 - (bx >> 5);           // global longest-first (64-row q tiles)
  int hb = bx & 31;
  int h = hb & 15, b = hb >> 4;
  int kvh = h >> 2;                  // G = 4
  int q0 = it * 64;
  int NT = it + 1;

  // Q fragments (also PV's qrow assignment): lane l16 = qrow
  short8 qf[2][4];
#pragma unroll
  for (int m = 0; m < 2; m++) {
    const u16* qb = qr + ((size_t)(b * S_ + q0 + rhalf * 32 + m * 16 + l16) * H_ + h) * HD_;
#pragma unroll
    for (int kk = 0; kk < 4; kk++)
      qf[m][kk] = *(const short8*)(qb + kk * 32 + quad * 8);
  }

  // K staging with permuted source rows (see header comment); stored-row&15
  // = R0, so the chunk^row swizzle (gjk) is unchanged.
  int R0 = tid >> 4;
  int base_act = (R0 >> 2) * 8 + (R0 & 3);
  int gjk = (tid & 15) ^ (R0 & 15);
  int gjv = (tid & 7) ^ ((tid >> 3) & 7);
  const u16* kp = kr + ((size_t)(b * S_ + base_act) * KVH_ + kvh) * HD_ + gjk * 8;
  const u16* vp = vt + ((size_t)(b * KVH_ + kvh) * HD_ + (tid >> 3)) * S_ + gjv * 8;
  const int joffK[4] = {0, 4, 32, 36};

  // prologue: stage tile 0 into buffer 0
#pragma unroll
  for (int j = 0; j < 4; j++) {
    GLDS16(kp + (size_t)joffK[j] * KVH_ * HD_, smem + (size_t)(j * 256 + tid) * 8);
    GLDS16(vp + (size_t)(j * 32) * S_,         smem + 16384 + (size_t)(j * 256 + tid) * 8);
  }
  kp += (size_t)64 * KVH_ * HD_;
  vp += 64;
  __syncthreads();                   // drains vmcnt(0): tile 0 ready

  floatx4 accO[2][8] = {};           // qrow = m*16+quad*4+r, d = ht*16+l16
  float lp[2] = { 0.f, 0.f };        // per-lane partial denom (qrow m*16+l16)

  const float LOG2E = 1.4426950408889634f;
  const float MBIAS = -12.5f * 1.4426950408889634f;
  int qmax = q0 + rhalf * 32 + 31;
  int qrow0 = q0 + rhalf * 32 + l16;

  for (int kt = 0; kt < NT; kt++) {
    if (kt + 1 < NT) {
      u16* KD = smem + (size_t)((kt + 1) & 1) * 8192;
      u16* VD = smem + 16384 + (size_t)((kt + 1) & 1) * 8192;
#pragma unroll
      for (int j = 0; j < 4; j++) {
        GLDS16(kp + (size_t)joffK[j] * KVH_ * HD_, KD + (size_t)(j * 256 + tid) * 8);
        GLDS16(vp + (size_t)(j * 32) * S_,         VD + (size_t)(j * 256 + tid) * 8);
      }
      kp += (size_t)64 * KVH_ * HD_;
      vp += 64;
    }

    int k0 = kt * 64;
    int s0w = k0 + shalf * 32;
    if (s0w <= qmax) {               // wave-uniform skip of fully-masked tiles
      const u16* KsC = smem + (size_t)(kt & 1) * 8192;
      const u16* VtC = smem + 16384 + (size_t)(kt & 1) * 8192;

      // QK^T swapped: A = K (rows = stored kcols), B = Q (cols = qrows)
      floatx4 sacc[2][2] = {};
      __builtin_amdgcn_s_setprio(1);
#pragma unroll
      for (int kk = 0; kk < 4; kk++) {
        short8 kf[2];
#pragma unroll
        for (int nt = 0; nt < 2; nt++) {
          int row = shalf * 32 + nt * 16 + l16;
          kf[nt] = *(const short8*)&KsC[row * 128 + (((kk * 4 + quad) ^ (row & 15)) * 8)];
        }
#pragma unroll
        for (int nt = 0; nt < 2; nt++) {
          sacc[0][nt] = __builtin_amdgcn_mfma_f32_16x16x32_bf16(kf[nt], qf[0][kk], sacc[0][nt], 0, 0, 0);
          sacc[1][nt] = __builtin_amdgcn_mfma_f32_16x16x32_bf16(kf[nt], qf[1][kk], sacc[1][nt], 0, 0, 0);
        }
      }
      __builtin_amdgcn_s_setprio(0);

      // softmax fully in-register.  Actual local kcol of sacc[m][nt][r] at
      // this lane = quad*8 + nt*4 + r (by the staging permutation).
      bool diag = (s0w + 31 > q0 + rhalf * 32);
      int kb = s0w + quad * 8;
      short8 pf[2];
#pragma unroll
      for (int m = 0; m < 2; m++) {
        int qrow = qrow0 + m * 16;
        float ps[8];
        float rsum = 0.f;
#pragma unroll
        for (int nti = 0; nti < 2; nti++)
#pragma unroll
          for (int r = 0; r < 4; r++) {
            float p = __builtin_amdgcn_exp2f(fmaf(sacc[m][nti][r], LOG2E, MBIAS));
            if (diag && (kb + nti * 4 + r) > qrow) p = 0.f;
            ps[nti * 4 + r] = p;
            rsum += p;
          }
        lp[m] += rsum;
        union { unsigned int w[4]; short8 s; } pk_;
#pragma unroll
        for (int c = 0; c < 4; c++)
          asm("v_cvt_pk_bf16_f32 %0, %1, %2"
              : "=v"(pk_.w[c]) : "v"(ps[2 * c]), "v"(ps[2 * c + 1]));
        pf[m] = pk_.s;
      }

      // PV: A = P (in registers), B = V fragments; accO layout unchanged
      __builtin_amdgcn_s_setprio(1);
#pragma unroll
      for (int ht = 0; ht < 8; ht++) {
        int row = ht * 16 + l16;
        short8 vf = *(const short8*)&VtC[row * 64 + (((shalf * 4 + quad) ^ (row & 7)) * 8)];
        accO[0][ht] = __builtin_amdgcn_mfma_f32_16x16x32_bf16(pf[0], vf, accO[0][ht], 0, 0, 0);
        accO[1][ht] = __builtin_amdgcn_mfma_f32_16x16x32_bf16(pf[1], vf, accO[1][ht], 0, 0, 0);
      }
      __builtin_amdgcn_s_setprio(0);
    }
    __syncthreads();                 // readers done + next tile's GLDS drained
  }

  // full row sums: combine the 4 quads (lanes sharing l16 = same qrow)
#pragma unroll
  for (int m = 0; m < 2; m++) {
    lp[m] += __shfl_xor(lp[m], 16);
    lp[m] += __shfl_xor(lp[m], 32);
  }

  // combine wave w (s-half 0) with wave w+2 (s-half 1) via LDS overlay.
  floatx4* xch = (floatx4*)(void*)smem;          // 32 KB overlay on K dbuf
  if (wid >= 2) {
    floatx4* dst = xch + ((wid & 1) * 1024 + lane * 16);
#pragma unroll
    for (int m = 0; m < 2; m++)
#pragma unroll
      for (int ht = 0; ht < 8; ht++)
        dst[(m * 8 + ht + lane) & 15] = accO[m][ht];
    if (lane < 16) {
#pragma unroll
      for (int m = 0; m < 2; m++)
        lpbuf[(wid & 1) * 32 + m * 16 + lane] = lp[m];
    }
  }
  __syncthreads();
  if (wid < 2) {
    floatx4* src = xch + (wid * 1024 + lane * 16);
    float inv[2][4];
#pragma unroll
    for (int m = 0; m < 2; m++)
#pragma unroll
      for (int ht = 0; ht < 8; ht++)
        accO[m][ht] += src[(m * 8 + ht + lane) & 15];
#pragma unroll
    for (int m = 0; m < 2; m++)
#pragma unroll
      for (int r = 0; r < 4; r++) {
        float own = __shfl(lp[m], quad * 4 + r);   // lane quad*4+r holds qrow m*16+(quad*4+r)
        inv[m][r] = 1.0f / (own + lpbuf[wid * 32 + m * 16 + quad * 4 + r]);
      }
#pragma unroll
    for (int m = 0; m < 2; m++)
#pragma unroll
      for (int ht = 0; ht < 8; ht++)
#pragma unroll
        for (int r = 0; r < 4; r++) {
          int row = q0 + wid * 32 + m * 16 + quad * 4 + r;
          att[((size_t)(b * S_ + row) * H_ + h) * HD_ + ht * 16 + l16] =
              f2bf(accO[m][ht][r] * inv[m][r]);
        }
  }
}

// ---------------------------------------------------------------------------
extern "C" void kernel_launch(void* const* d_in, const int* in_sizes, int n_in,
                              void* d_out, int out_size, void* d_ws, size_t ws_size,
                              hipStream_t stream)
{
  const float* x  = (const float*)d_in[0];   // [B,S,DM] f32
  const float* wq = (const float*)d_in[1];   // [DM, H*HD] f32
  const float* wk = (const float*)d_in[2];   // [DM, KV*HD] f32
  const float* wv = (const float*)d_in[3];   // [DM, KV*HD] f32
  const float* wo = (const float*)d_in[4];   // [H*HD, DM] f32
  const float* qs = (const float*)d_in[5];   // [HD] f32
  const float* ks = (const float*)d_in[6];   // [HD] f32

  char* ws = (char*)d_ws;
  size_t off = 0;
  u16* x_bf   = (u16*)(ws + off); off += (size_t)4096 * 2048 * 2;   // x bf16
  u16* wqkv_t = (u16*)(ws + off); off += (size_t)3072 * 2048 * 2;   // [3072][2048]
  u16* wo_t   = (u16*)(ws + off); off += (size_t)2048 * 2048 * 2;   // [2048][2048]
  u16* q_rope = (u16*)(ws + off); off += (size_t)4096 * 16 * 128 * 2;
  u16* k_rope = (u16*)(ws + off); off += (size_t)4096 * 4 * 128 * 2;
  u16* vt     = (u16*)(ws + off); off += (size_t)8 * 128 * 2048 * 2;
  u16* att    = (u16*)(ws + off); off += (size_t)4096 * 2048 * 2;
  float2* rope_tab = (float2*)(ws + off); off += (size_t)2048 * 64 * 8;  // 1 MB

  // pack x + weight transposes + rope table, one launch
  k_prep<<<dim3(18944), 256, 0, stream>>>(x, wq, wk, wv, wo, x_bf, wqkv_t, wo_t, rope_tab);

  // qkv = x @ [wq|wk|wv]; fused RMSNorm+RoPE (q/k) and v-transpose (v)
  k_gemm_qkv<<<dim3(24, 32), 256, 0, stream>>>(x_bf, wqkv_t, qs, ks, rope_tab,
                                               q_rope, k_rope, vt);

  // causal flash: 1024 blocks x 4 waves (64 q-rows/block), longest-first
  k_flash<<<dim3(1024), 256, 0, stream>>>(q_rope, k_rope, vt, att);

  // out = att @ wo  (f32 out, matching reference output dtype)
  k_gemm_bt<<<dim3(16, 32), 256, 0, stream>>>(att, wo_t, d_out, 4096, 2048, 2048, 0);

  (void)in_sizes; (void)n_in; (void)out_size; (void)ws_size;
}